// Round 6
// baseline (201.064 us; speedup 1.0000x reference)
//
#include <hip/hip_runtime.h>
#include <cstddef>

#define NEDGES   800000
#define NRAD     32
#define MAXZ     100
#define T1_OFF   0
#define T2_OFF   (MAXZ * 128)                    // 12800 floats
#define WC_OFF   (2 * MAXZ * 128)                // 25600 floats
#define FB_OFF   (2 * MAXZ * 128 + NRAD * 128)   // 29696 floats (B-frags, 8KB)
#define ZP_OFF   (FB_OFF + 2048)                 // 31744 floats, then 800000 ints

#define LDS_RS   132                             // padded row stride (2-way only)

typedef __attribute__((ext_vector_type(8))) short bf16x8;
typedef __attribute__((ext_vector_type(4))) float f32x4;

__device__ inline unsigned short f2bf(float f) {            // RTNE f32->bf16
    unsigned u = __float_as_uint(f);
    u += 0x7FFFu + ((u >> 16) & 1u);
    return (unsigned short)(u >> 16);
}
__device__ inline float bf2f(unsigned short h) {
    return __uint_as_float(((unsigned)h) << 16);
}
__device__ inline float silu(float v) {
    return v * __builtin_amdgcn_rcpf(1.f + __expf(-v));
}

// ---------------------------------------------------------------------------
// Prep A: fold weights into tables.
// ---------------------------------------------------------------------------
__global__ __launch_bounds__(128)
void prep_kernel(const float* __restrict__ embed_w,
                 const float* __restrict__ w_rbf,
                 const float* __restrict__ w_edge,
                 const float* __restrict__ b_edge,
                 float* __restrict__ ws) {
    const int d = threadIdx.x;
    const int b = blockIdx.x;
    if (b < MAXZ) {
        float a1 = b_edge[d];
        float a2 = 0.f;
        #pragma unroll 8
        for (int k = 0; k < 128; ++k) {
            const float e = embed_w[b * 128 + k];
            a1 = fmaf(e, w_edge[k * 128 + d], a1);
            a2 = fmaf(e, w_edge[(128 + k) * 128 + d], a2);
        }
        ws[T1_OFF + b * 128 + d] = a1;
        ws[T2_OFF + b * 128 + d] = a2;
    } else {
        const int q = b - MAXZ;
        float a = 0.f;
        #pragma unroll 8
        for (int m = 0; m < 128; ++m)
            a = fmaf(w_rbf[q * 128 + m], w_edge[(256 + m) * 128 + d], a);
        ws[WC_OFF + q * 128 + d] = a;
    }
}

// ---------------------------------------------------------------------------
// Prep B: B-fragments of Wc in MFMA lane order (coalesced 16B loads later).
// ---------------------------------------------------------------------------
__global__ __launch_bounds__(512)
void prep_b_kernel(const float* __restrict__ ws_in, float* __restrict__ ws) {
    const int tid  = threadIdx.x;
    const int g    = tid >> 6;
    const int lane = tid & 63;
    const int n16  = lane & 15;
    const int kh   = lane >> 4;
    unsigned short* FB = (unsigned short*)(ws + FB_OFF);
    #pragma unroll
    for (int j = 0; j < 8; ++j)
        FB[(g * 64 + lane) * 8 + j] =
            f2bf(ws_in[WC_OFF + (kh * 8 + j) * 128 + 16 * g + n16]);
}

__global__ __launch_bounds__(256)
void zp_kernel(const int* __restrict__ x,
               const int* __restrict__ idx_i,
               const int* __restrict__ idx_j,
               int* __restrict__ zp) {
    const int e = blockIdx.x * 256 + threadIdx.x;
    zp[e] = (x[idx_j[e]] << 8) | x[idx_i[e]];
}

// ---------------------------------------------------------------------------
// Main: one 16-edge group per wave, no loop (TLP). MFMA for rbf@Wc, then
// transpose the C-tile through per-wave LDS so every store is FULLY DENSE:
//   - 8 stores/wave, each 2 complete 512B rows (1KB dense)
//   - T1/T2 gathers: 2 dense 512B row-reads per instruction (float4/lane)
//   - VMEM/wave: 38 instrs (was ~107, quarter-dense stores)
// ---------------------------------------------------------------------------
__global__ __launch_bounds__(256, 4)
void edge_kernel(const float* __restrict__ rbf,
                 const int* __restrict__ zp,
                 const float* __restrict__ ws,
                 float* __restrict__ out) {
    __shared__ float tile[4 * 16 * LDS_RS];      // 33.8 KB, per-wave private

    const int lane = threadIdx.x & 63;
    const int wid  = threadIdx.x >> 6;
    const int n16  = lane & 15;
    const int kh   = lane >> 4;
    const int grp  = blockIdx.x * 4 + wid;
    const int ebase = __builtin_amdgcn_readfirstlane(grp * 16);

    const float* __restrict__ T1 = ws + T1_OFF;
    const float* __restrict__ T2 = ws + T2_OFF;
    const bf16x8* __restrict__ FB = (const bf16x8*)(ws + FB_OFF);
    float* const wtile = tile + wid * 16 * LDS_RS;

    // A fragment first (longest latency: HBM)
    const float* arow = rbf + (size_t)(ebase + n16) * NRAD + kh * 8;
    const float4 a04 = *(const float4*)(arow);
    const float4 a44 = *(const float4*)(arow + 4);

    // B fragments: 8 coalesced 16B loads (L2-hot)
    bf16x8 bhi[8];
    #pragma unroll
    for (int g = 0; g < 8; ++g)
        bhi[g] = FB[g * 64 + lane];

    // all 16 zp values for this group (L2-hot, wave-uniform address)
    const int4 z0 = *(const int4*)(zp + ebase);
    const int4 z1 = *(const int4*)(zp + ebase + 4);
    const int4 z2 = *(const int4*)(zp + ebase + 8);
    const int4 z3 = *(const int4*)(zp + ebase + 12);
    const int za[16] = {z0.x, z0.y, z0.z, z0.w, z1.x, z1.y, z1.z, z1.w,
                        z2.x, z2.y, z2.z, z2.w, z3.x, z3.y, z3.z, z3.w};

    const float av[8] = {a04.x, a04.y, a04.z, a04.w,
                         a44.x, a44.y, a44.z, a44.w};
    bf16x8 ahi, alo;
    #pragma unroll
    for (int j = 0; j < 8; ++j) {
        const unsigned short h = f2bf(av[j]);
        ahi[j] = (short)h;
        alo[j] = (short)f2bf(av[j] - bf2f(h));
    }

    f32x4 acc[8];
    #pragma unroll
    for (int g = 0; g < 8; ++g) {
        acc[g] = (f32x4){0.f, 0.f, 0.f, 0.f};
        acc[g] = __builtin_amdgcn_mfma_f32_16x16x32_bf16(ahi, bhi[g], acc[g], 0, 0, 0);
        acc[g] = __builtin_amdgcn_mfma_f32_16x16x32_bf16(alo, bhi[g], acc[g], 0, 0, 0);
    }

    // C layout: row = kh*4 + r, col = 16g + n16  -> LDS (2-way conflicts max)
    #pragma unroll
    for (int g = 0; g < 8; ++g)
        #pragma unroll
        for (int r = 0; r < 4; ++r)
            wtile[(kh * 4 + r) * LDS_RS + 16 * g + n16] = acc[g][r];

    __syncthreads();

    // Read back transposed: lane owns col-chunk 4*(lane&31), rows 2j+(lane>>5)
    const int ls = lane >> 5;
    const int cw = (lane & 31) * 4;

    #pragma unroll
    for (int j = 0; j < 8; ++j) {
        const int row = 2 * j + ls;
        const int zpv = ls ? za[2 * j + 1] : za[2 * j];
        const int zj  = zpv >> 8;
        const int zi  = zpv & 0xFF;

        const float4 c  = *(const float4*)(wtile + row * LDS_RS + cw);
        const float4 u1 = *(const float4*)(T1 + zj * 128 + cw);
        const float4 u2 = *(const float4*)(T2 + zi * 128 + cw);

        float4 o;
        o.x = silu(c.x + u1.x + u2.x);
        o.y = silu(c.y + u1.y + u2.y);
        o.z = silu(c.z + u1.z + u2.z);
        o.w = silu(c.w + u1.w + u2.w);

        *(float4*)(out + (size_t)(ebase + row) * 128 + cw) = o;
    }
}

extern "C" void kernel_launch(void* const* d_in, const int* in_sizes, int n_in,
                              void* d_out, int out_size, void* d_ws, size_t ws_size,
                              hipStream_t stream) {
    const int*   x       = (const int*)d_in[0];
    const float* rbf     = (const float*)d_in[1];
    const int*   idx_i   = (const int*)d_in[2];
    const int*   idx_j   = (const int*)d_in[3];
    const float* embed_w = (const float*)d_in[4];
    const float* w_rbf   = (const float*)d_in[5];
    const float* w_edge  = (const float*)d_in[6];
    const float* b_edge  = (const float*)d_in[7];
    float* out = (float*)d_out;
    float* ws  = (float*)d_ws;
    int*   zp  = (int*)(ws + ZP_OFF);

    prep_kernel<<<MAXZ + NRAD, 128, 0, stream>>>(embed_w, w_rbf, w_edge, b_edge, ws);
    prep_b_kernel<<<1, 512, 0, stream>>>(ws, ws);
    zp_kernel<<<NEDGES / 256, 256, 0, stream>>>(x, idx_i, idx_j, zp);
    edge_kernel<<<NEDGES / 64, 256, 0, stream>>>(rbf, zp, ws, out);
}

// Round 7
// 200.196 us; speedup vs baseline: 1.0043x; 1.0043x over previous
//
#include <hip/hip_runtime.h>
#include <cstddef>

#define NEDGES   800000
#define NRAD     32
#define MAXZ     100
#define T1_OFF   0
#define T2_OFF   (MAXZ * 128)                    // 12800 floats
#define WC_OFF   (2 * MAXZ * 128)                // 25600 floats
#define FB_OFF   (2 * MAXZ * 128 + NRAD * 128)   // 29696 floats (B-frags, 8KB)
#define ZP_OFF   (FB_OFF + 2048)                 // 31744 floats, then 800000 ints

#define LDS_RS   132                             // padded row stride

typedef __attribute__((ext_vector_type(8))) short bf16x8;
typedef __attribute__((ext_vector_type(4))) float f32x4;

__device__ inline unsigned short f2bf(float f) {            // RTNE f32->bf16
    unsigned u = __float_as_uint(f);
    u += 0x7FFFu + ((u >> 16) & 1u);
    return (unsigned short)(u >> 16);
}
__device__ inline float silu(float v) {
    return v * __builtin_amdgcn_rcpf(1.f + __expf(-v));
}

// ---------------------------------------------------------------------------
// Prep A: fold weights into tables.
// ---------------------------------------------------------------------------
__global__ __launch_bounds__(128)
void prep_kernel(const float* __restrict__ embed_w,
                 const float* __restrict__ w_rbf,
                 const float* __restrict__ w_edge,
                 const float* __restrict__ b_edge,
                 float* __restrict__ ws) {
    const int d = threadIdx.x;
    const int b = blockIdx.x;
    if (b < MAXZ) {
        float a1 = b_edge[d];
        float a2 = 0.f;
        #pragma unroll 8
        for (int k = 0; k < 128; ++k) {
            const float e = embed_w[b * 128 + k];
            a1 = fmaf(e, w_edge[k * 128 + d], a1);
            a2 = fmaf(e, w_edge[(128 + k) * 128 + d], a2);
        }
        ws[T1_OFF + b * 128 + d] = a1;
        ws[T2_OFF + b * 128 + d] = a2;
    } else {
        const int q = b - MAXZ;
        float a = 0.f;
        #pragma unroll 8
        for (int m = 0; m < 128; ++m)
            a = fmaf(w_rbf[q * 128 + m], w_edge[(256 + m) * 128 + d], a);
        ws[WC_OFF + q * 128 + d] = a;
    }
}

// ---------------------------------------------------------------------------
// Prep B: B-fragments of Wc in MFMA lane order (coalesced 16B loads later).
// ---------------------------------------------------------------------------
__global__ __launch_bounds__(512)
void prep_b_kernel(const float* __restrict__ ws_in, float* __restrict__ ws) {
    const int tid  = threadIdx.x;
    const int g    = tid >> 6;
    const int lane = tid & 63;
    const int n16  = lane & 15;
    const int kh   = lane >> 4;
    unsigned short* FB = (unsigned short*)(ws + FB_OFF);
    #pragma unroll
    for (int j = 0; j < 8; ++j)
        FB[(g * 64 + lane) * 8 + j] =
            f2bf(ws_in[WC_OFF + (kh * 8 + j) * 128 + 16 * g + n16]);
}

__global__ __launch_bounds__(256)
void zp_kernel(const int* __restrict__ x,
               const int* __restrict__ idx_i,
               const int* __restrict__ idx_j,
               int* __restrict__ zp) {
    const int e = blockIdx.x * 256 + threadIdx.x;
    zp[e] = (x[idx_j[e]] << 8) | x[idx_i[e]];
}

// ---------------------------------------------------------------------------
// Main: one 16-edge group per wave, no loop (pure TLP).
//   - single bf16 MFMA per col-group (8 total; lo-part dropped, absmax budget ok)
//   - wave-PRIVATE LDS transpose, NO __syncthreads (waves stay decoupled)
//   - NONTEMPORAL stores for out + nt loads for rbf: the 403MB write stream
//     and 102MB read stream bypass L2 allocation, keeping L2 for T1/T2/FB.
// ---------------------------------------------------------------------------
__global__ __launch_bounds__(256, 4)
void edge_kernel(const float* __restrict__ rbf,
                 const int* __restrict__ zp,
                 const float* __restrict__ ws,
                 float* __restrict__ out) {
    __shared__ float tile[4 * 16 * LDS_RS];      // 33.8 KB, per-wave slices

    const int lane = threadIdx.x & 63;
    const int wid  = threadIdx.x >> 6;
    const int n16  = lane & 15;
    const int kh   = lane >> 4;
    const int grp  = blockIdx.x * 4 + wid;
    const int ebase = __builtin_amdgcn_readfirstlane(grp * 16);

    const float* __restrict__ T1 = ws + T1_OFF;
    const float* __restrict__ T2 = ws + T2_OFF;
    const bf16x8* __restrict__ FB = (const bf16x8*)(ws + FB_OFF);
    float* const wtile = tile + wid * 16 * LDS_RS;

    // A tile: rbf[ebase+n16][kh*8 .. kh*8+7], nontemporal (stream-once data)
    const f32x4* arow = (const f32x4*)(rbf + (size_t)(ebase + n16) * NRAD + kh * 8);
    const f32x4 a04 = __builtin_nontemporal_load(arow);
    const f32x4 a44 = __builtin_nontemporal_load(arow + 1);

    // B fragments: 8 coalesced 16B loads (L2-hot)
    bf16x8 bhi[8];
    #pragma unroll
    for (int g = 0; g < 8; ++g)
        bhi[g] = FB[g * 64 + lane];

    // all 16 zp values (L2-hot, wave-uniform address)
    const int4 z0 = *(const int4*)(zp + ebase);
    const int4 z1 = *(const int4*)(zp + ebase + 4);
    const int4 z2 = *(const int4*)(zp + ebase + 8);
    const int4 z3 = *(const int4*)(zp + ebase + 12);
    const int za[16] = {z0.x, z0.y, z0.z, z0.w, z1.x, z1.y, z1.z, z1.w,
                        z2.x, z2.y, z2.z, z2.w, z3.x, z3.y, z3.z, z3.w};

    bf16x8 ahi;
    ahi[0] = (short)f2bf(a04.x); ahi[1] = (short)f2bf(a04.y);
    ahi[2] = (short)f2bf(a04.z); ahi[3] = (short)f2bf(a04.w);
    ahi[4] = (short)f2bf(a44.x); ahi[5] = (short)f2bf(a44.y);
    ahi[6] = (short)f2bf(a44.z); ahi[7] = (short)f2bf(a44.w);

    f32x4 acc[8];
    #pragma unroll
    for (int g = 0; g < 8; ++g) {
        acc[g] = (f32x4){0.f, 0.f, 0.f, 0.f};
        acc[g] = __builtin_amdgcn_mfma_f32_16x16x32_bf16(ahi, bhi[g], acc[g], 0, 0, 0);
    }

    // C layout: row = kh*4 + r, col = 16g + n16 -> wave-private LDS slice.
    // No barrier: intra-wave write->read, compiler inserts lgkmcnt waits.
    #pragma unroll
    for (int g = 0; g < 8; ++g)
        #pragma unroll
        for (int r = 0; r < 4; ++r)
            wtile[(kh * 4 + r) * LDS_RS + 16 * g + n16] = acc[g][r];

    // Read back transposed: lane owns col-chunk 4*(lane&31), rows 2j+(lane>>5)
    const int ls = lane >> 5;
    const int cw = (lane & 31) * 4;

    #pragma unroll
    for (int j = 0; j < 8; ++j) {
        const int row = 2 * j + ls;
        const int zpv = ls ? za[2 * j + 1] : za[2 * j];
        const int zj  = zpv >> 8;
        const int zi  = zpv & 0xFF;

        const float4 c  = *(const float4*)(wtile + row * LDS_RS + cw);
        const float4 u1 = *(const float4*)(T1 + zj * 128 + cw);
        const float4 u2 = *(const float4*)(T2 + zi * 128 + cw);

        f32x4 o;
        o.x = silu(c.x + u1.x + u2.x);
        o.y = silu(c.y + u1.y + u2.y);
        o.z = silu(c.z + u1.z + u2.z);
        o.w = silu(c.w + u1.w + u2.w);

        // nontemporal: don't allocate the 403MB stream in L2
        __builtin_nontemporal_store(o, (f32x4*)(out + (size_t)(ebase + row) * 128 + cw));
    }
}

extern "C" void kernel_launch(void* const* d_in, const int* in_sizes, int n_in,
                              void* d_out, int out_size, void* d_ws, size_t ws_size,
                              hipStream_t stream) {
    const int*   x       = (const int*)d_in[0];
    const float* rbf     = (const float*)d_in[1];
    const int*   idx_i   = (const int*)d_in[2];
    const int*   idx_j   = (const int*)d_in[3];
    const float* embed_w = (const float*)d_in[4];
    const float* w_rbf   = (const float*)d_in[5];
    const float* w_edge  = (const float*)d_in[6];
    const float* b_edge  = (const float*)d_in[7];
    float* out = (float*)d_out;
    float* ws  = (float*)d_ws;
    int*   zp  = (int*)(ws + ZP_OFF);

    prep_kernel<<<MAXZ + NRAD, 128, 0, stream>>>(embed_w, w_rbf, w_edge, b_edge, ws);
    prep_b_kernel<<<1, 512, 0, stream>>>(ws, ws);
    zp_kernel<<<NEDGES / 256, 256, 0, stream>>>(x, idx_i, idx_j, zp);
    edge_kernel<<<NEDGES / 64, 256, 0, stream>>>(rbf, zp, ws, out);
}